// Round 1
// baseline (16523.351 us; speedup 1.0000x reference)
//
#include <hip/hip_runtime.h>
#include <math.h>

// ---------------------------------------------------------------------------
// VardaGPT associative forward: kNN retrieve -> fc fuse -> GPT-2 (12L) -> lm_head
// B=2 T=512 D=768 M=10000 K=5 L=12 H=12 V=50257 P=1024, all fp32.
// v1: correctness-first fp32 tiled GEMMs (no MFMA on fp32 in CDNA4).
// ---------------------------------------------------------------------------

#define DEVFN static __device__ __forceinline__

constexpr int CB = 2;        // batch
constexpr int CT = 512;      // seq len
constexpr int CD = 768;      // model dim
constexpr int CM = 10000;    // memory rows per batch
constexpr int CK = 5;        // top-k
constexpr int CL = 12;       // layers
constexpr int CH = 12;       // heads
constexpr int CHD = 64;      // head dim
constexpr int CV = 50257;    // vocab
constexpr int CFF = 3072;    // 4*D
constexpr int C3D = 2304;    // 3*D
constexpr int CIN = CD + CK * CD;  // 4608
constexpr float CSCALE = 0.125f;   // 1/sqrt(64)

enum { EPI_NONE = 0, EPI_BIAS = 1, EPI_SCORES = 2, EPI_BIAS_WPE = 3,
       EPI_BIAS_RES = 4, EPI_BIAS_GELU = 5, EPI_SCALE = 6 };

// ---------------------------------------------------------------------------
// Generic tiled GEMM:  C[m,n] = sum_k A[m,k] * B[k,n]   (BT=false, B is [K,N])
//                      C[m,n] = sum_k A[m,k] * B[n,k]   (BT=true,  B is [N,K])
// Batched via grid.z: z -> (zb = z/H2, zh = z%H2), element strides given.
// M and K must be multiples of BM/BK (true for all uses); N is guarded.
// ---------------------------------------------------------------------------
template <int BM, int BN, int BK, int TM, int TN, bool BT, int EPI>
__global__ __launch_bounds__(256) void gemm_k(
    const float* __restrict__ A, const float* __restrict__ Bp,
    const float* __restrict__ bias, const float* __restrict__ extra,
    float* __restrict__ C,
    int Mdim, int Ndim, int Kdim, int lda, int ldb, int ldc,
    int H2, long sAb, long sAh, long sBb, long sBh, long sCb, long sCh,
    float p0) {
  const int n0 = blockIdx.x * BN;
  const int m0 = blockIdx.y * BM;
  if (EPI == EPI_SCALE && n0 > m0 + BM - 1) return;  // fully-masked causal tile

  const int z = blockIdx.z;
  const int zb = z / H2, zh = z % H2;
  A  += (long)zb * sAb + (long)zh * sAh;
  Bp += (long)zb * sBb + (long)zh * sBh;
  float* Cz = C + (long)zb * sCb + (long)zh * sCh;

  __shared__ float As[BK][BM + 4];
  __shared__ float Bs[BK][BN + 4];

  const int tid = threadIdx.x;
  const int tx = tid % (BN / TN);
  const int ty = tid / (BN / TN);

  float acc[TM][TN];
#pragma unroll
  for (int i = 0; i < TM; ++i)
#pragma unroll
    for (int j = 0; j < TN; ++j) acc[i][j] = 0.f;

  for (int k0 = 0; k0 < Kdim; k0 += BK) {
    // ---- load A tile (BM x BK), store transposed As[k][m]
    constexpr int AIT = (BM * BK / 4 + 255) / 256;
#pragma unroll
    for (int it = 0; it < AIT; ++it) {
      int s = tid + it * 256;
      if (s < BM * BK / 4) {
        int row = s / (BK / 4);
        int kg = (s % (BK / 4)) * 4;
        float4 v = *reinterpret_cast<const float4*>(A + (long)(m0 + row) * lda + k0 + kg);
        As[kg + 0][row] = v.x;
        As[kg + 1][row] = v.y;
        As[kg + 2][row] = v.z;
        As[kg + 3][row] = v.w;
      }
    }
    // ---- load B tile
    constexpr int BIT = (BN * BK / 4 + 255) / 256;
    if (BT) {
#pragma unroll
      for (int it = 0; it < BIT; ++it) {
        int s = tid + it * 256;
        if (s < BN * BK / 4) {
          int row = s / (BK / 4);
          int kg = (s % (BK / 4)) * 4;
          float4 v = make_float4(0.f, 0.f, 0.f, 0.f);
          if (n0 + row < Ndim)
            v = *reinterpret_cast<const float4*>(Bp + (long)(n0 + row) * ldb + k0 + kg);
          Bs[kg + 0][row] = v.x;
          Bs[kg + 1][row] = v.y;
          Bs[kg + 2][row] = v.z;
          Bs[kg + 3][row] = v.w;
        }
      }
    } else {
#pragma unroll
      for (int it = 0; it < BIT; ++it) {
        int s = tid + it * 256;
        if (s < BN * BK / 4) {
          int krow = s / (BN / 4);
          int ng = (s % (BN / 4)) * 4;
          const float* src = Bp + (long)(k0 + krow) * ldb + n0 + ng;
          float4 v;
          if (n0 + ng + 3 < Ndim) {
            v = *reinterpret_cast<const float4*>(src);
          } else {
            v.x = (n0 + ng + 0 < Ndim) ? src[0] : 0.f;
            v.y = (n0 + ng + 1 < Ndim) ? src[1] : 0.f;
            v.z = (n0 + ng + 2 < Ndim) ? src[2] : 0.f;
            v.w = (n0 + ng + 3 < Ndim) ? src[3] : 0.f;
          }
          *reinterpret_cast<float4*>(&Bs[krow][ng]) = v;
        }
      }
    }
    __syncthreads();

#pragma unroll
    for (int k = 0; k < BK; ++k) {
      float ra[TM], rb[TN];
#pragma unroll
      for (int i = 0; i < TM; ++i) ra[i] = As[k][ty * TM + i];
#pragma unroll
      for (int j = 0; j < TN; ++j) rb[j] = Bs[k][tx * TN + j];
#pragma unroll
      for (int i = 0; i < TM; ++i)
#pragma unroll
        for (int j = 0; j < TN; ++j) acc[i][j] += ra[i] * rb[j];
    }
    __syncthreads();
  }

  // ---- epilogue
#pragma unroll
  for (int i = 0; i < TM; ++i) {
    const int m = m0 + ty * TM + i;
#pragma unroll
    for (int j = 0; j < TN; ++j) {
      const int n = n0 + tx * TN + j;
      if (n >= Ndim) continue;
      float v = acc[i][j];
      if (EPI == EPI_BIAS || EPI == EPI_BIAS_WPE || EPI == EPI_BIAS_RES ||
          EPI == EPI_BIAS_GELU)
        v += bias[n];
      if (EPI == EPI_SCORES) v = 2.f * v - extra[(long)zb * Ndim + n];
      if (EPI == EPI_BIAS_WPE) v += extra[(long)(m % CT) * Ndim + n];
      if (EPI == EPI_BIAS_RES)
        v += extra[(long)zb * sCb + (long)zh * sCh + (long)m * ldc + n];
      if (EPI == EPI_BIAS_GELU) {
        float x = v;
        v = 0.5f * x * (1.f + tanhf(0.7978845608028654f * (x + 0.044715f * x * x * x)));
      }
      if (EPI == EPI_SCALE) v = v * p0;
      Cz[(long)m * ldc + n] = v;
    }
  }
}

// ---------------------------------------------------------------------------
// memory row squared norms: norms[b*M+m] = sum_d memory[b,m,d]^2
// ---------------------------------------------------------------------------
__global__ __launch_bounds__(256) void norms_k(const float* __restrict__ mem,
                                               float* __restrict__ norms) {
  __shared__ float red[256];
  const int row = blockIdx.x;
  const int tid = threadIdx.x;
  const float* r = mem + (long)row * CD;
  float s = 0.f;
  for (int i = tid; i < CD; i += 256) {
    float v = r[i];
    s += v * v;
  }
  red[tid] = s;
  __syncthreads();
  for (int off = 128; off > 0; off >>= 1) {
    if (tid < off) red[tid] += red[tid + off];
    __syncthreads();
  }
  if (tid == 0) norms[row] = red[0];
}

// ---------------------------------------------------------------------------
// exact top-5 per row of scores[row, 0..M), lax.top_k tie semantics
// (descending score; ties -> ascending index)
// ---------------------------------------------------------------------------
DEVFN bool tk_better(float as, int ai, float bs, int bi) {
  return (as > bs) || (as == bs && ai < bi);
}
DEVFN void tk_insert(float s[5], int id[5], float cs, int ci) {
  if (!tk_better(cs, ci, s[4], id[4])) return;
  s[4] = cs;
  id[4] = ci;
#pragma unroll
  for (int j = 4; j > 0; --j) {
    if (tk_better(s[j], id[j], s[j - 1], id[j - 1])) {
      float ts = s[j]; s[j] = s[j - 1]; s[j - 1] = ts;
      int ti = id[j]; id[j] = id[j - 1]; id[j - 1] = ti;
    }
  }
}

__global__ __launch_bounds__(256) void topk_k(const float* __restrict__ scores,
                                              int* __restrict__ out) {
  __shared__ float ss[256 * 5];
  __shared__ int si[256 * 5];
  const int row = blockIdx.x;  // b*T + t
  const int tid = threadIdx.x;
  const float* sr = scores + (long)row * CM;
  float bs[5];
  int bi[5];
#pragma unroll
  for (int j = 0; j < 5; ++j) {
    bs[j] = -3.0e38f;
    bi[j] = 0x7fffffff;
  }
  for (int m = tid; m < CM; m += 256) tk_insert(bs, bi, sr[m], m);
#pragma unroll
  for (int j = 0; j < 5; ++j) {
    ss[tid * 5 + j] = bs[j];
    si[tid * 5 + j] = bi[j];
  }
  __syncthreads();
  if (tid == 0) {
    float fs[5];
    int fi[5];
#pragma unroll
    for (int j = 0; j < 5; ++j) {
      fs[j] = -3.0e38f;
      fi[j] = 0x7fffffff;
    }
    for (int c = 0; c < 256 * 5; ++c) tk_insert(fs, fi, ss[c], si[c]);
#pragma unroll
    for (int j = 0; j < 5; ++j) out[row * CK + j] = fi[j];
  }
}

// ---------------------------------------------------------------------------
// gather: xc[row] = concat(input[row], memory[b, idx[0..4], :])
// ---------------------------------------------------------------------------
__global__ __launch_bounds__(256) void gather_k(const float* __restrict__ inp,
                                                const float* __restrict__ mem,
                                                const int* __restrict__ idx,
                                                float* __restrict__ xc) {
  __shared__ int sid[5];
  const int row = blockIdx.x;  // b*T + t
  const int b = row / CT;
  const int tid = threadIdx.x;
  if (tid < 5) sid[tid] = idx[row * CK + tid];
  __syncthreads();
  float* dst = xc + (long)row * CIN;
  const float* s0 = inp + (long)row * CD;
  for (int i = tid; i < CD; i += 256) dst[i] = s0[i];
#pragma unroll
  for (int k = 0; k < 5; ++k) {
    const float* ms = mem + ((long)b * CM + sid[k]) * CD;
    for (int i = tid; i < CD; i += 256) dst[CD + k * CD + i] = ms[i];
  }
}

// ---------------------------------------------------------------------------
// LayerNorm row kernel (two-pass, eps=1e-5), D=768, block=256
// ---------------------------------------------------------------------------
__global__ __launch_bounds__(256) void ln_k(const float* __restrict__ x,
                                            const float* __restrict__ g,
                                            const float* __restrict__ bb,
                                            float* __restrict__ y) {
  __shared__ float red[256];
  const int row = blockIdx.x;
  const int tid = threadIdx.x;
  const float* xr = x + (long)row * CD;
  float v0 = xr[tid], v1 = xr[tid + 256], v2 = xr[tid + 512];
  red[tid] = v0 + v1 + v2;
  __syncthreads();
  for (int off = 128; off > 0; off >>= 1) {
    if (tid < off) red[tid] += red[tid + off];
    __syncthreads();
  }
  const float mu = red[0] * (1.f / 768.f);
  __syncthreads();
  const float d0 = v0 - mu, d1 = v1 - mu, d2 = v2 - mu;
  red[tid] = d0 * d0 + d1 * d1 + d2 * d2;
  __syncthreads();
  for (int off = 128; off > 0; off >>= 1) {
    if (tid < off) red[tid] += red[tid + off];
    __syncthreads();
  }
  const float rstd = rsqrtf(red[0] * (1.f / 768.f) + 1e-5f);
  float* yr = y + (long)row * CD;
  yr[tid] = d0 * rstd * g[tid] + bb[tid];
  yr[tid + 256] = d1 * rstd * g[tid + 256] + bb[tid + 256];
  yr[tid + 512] = d2 * rstd * g[tid + 512] + bb[tid + 512];
}

// ---------------------------------------------------------------------------
// causal softmax over S rows (in place). grid=(T, B*H), block=128.
// Masked (k>q) read as -1e9 (skipped tiles are never read), written as 0.
// ---------------------------------------------------------------------------
__global__ __launch_bounds__(128) void softmax_k(float* __restrict__ S) {
  __shared__ float red[128];
  const int q = blockIdx.x;
  const long base = (long)blockIdx.y * (CT * (long)CT) + (long)q * CT;
  const int tid = threadIdx.x;
  float v[4];
#pragma unroll
  for (int i = 0; i < 4; ++i) {
    int k = tid + i * 128;
    v[i] = (k <= q) ? S[base + k] : -1e9f;
  }
  float m = fmaxf(fmaxf(v[0], v[1]), fmaxf(v[2], v[3]));
  red[tid] = m;
  __syncthreads();
  for (int off = 64; off > 0; off >>= 1) {
    if (tid < off) red[tid] = fmaxf(red[tid], red[tid + off]);
    __syncthreads();
  }
  m = red[0];
  __syncthreads();
  float e[4];
  float sum = 0.f;
#pragma unroll
  for (int i = 0; i < 4; ++i) {
    e[i] = expf(v[i] - m);
    sum += e[i];
  }
  red[tid] = sum;
  __syncthreads();
  for (int off = 64; off > 0; off >>= 1) {
    if (tid < off) red[tid] += red[tid + off];
    __syncthreads();
  }
  const float inv = 1.f / red[0];
#pragma unroll
  for (int i = 0; i < 4; ++i) S[base + tid + i * 128] = e[i] * inv;
}

// ---------------------------------------------------------------------------
// launcher
// ---------------------------------------------------------------------------
extern "C" void kernel_launch(void* const* d_in, const int* in_sizes, int n_in,
                              void* d_out, int out_size, void* d_ws, size_t ws_size,
                              hipStream_t stream) {
  const float* input   = (const float*)d_in[0];
  const float* memory  = (const float*)d_in[1];
  const float* fc_w    = (const float*)d_in[2];
  const float* fc_b    = (const float*)d_in[3];
  const float* wpe     = (const float*)d_in[4];
  const float* wte     = (const float*)d_in[5];
  const float* ln1_g   = (const float*)d_in[6];
  const float* ln1_b   = (const float*)d_in[7];
  const float* attn_w  = (const float*)d_in[8];
  const float* attn_b  = (const float*)d_in[9];
  const float* proj_w  = (const float*)d_in[10];
  const float* proj_b  = (const float*)d_in[11];
  const float* ln2_g   = (const float*)d_in[12];
  const float* ln2_b   = (const float*)d_in[13];
  const float* mfc_w   = (const float*)d_in[14];
  const float* mfc_b   = (const float*)d_in[15];
  const float* mpj_w   = (const float*)d_in[16];
  const float* mpj_b   = (const float*)d_in[17];
  const float* lnf_g   = (const float*)d_in[18];
  const float* lnf_b   = (const float*)d_in[19];
  float* out = (float*)d_out;
  char* ws = (char*)d_ws;

  // workspace layout (time-overlapped; peak ~61 MB)
  int*   topk   = (int*)(ws);                        // 20 KB          [persist phase 1]
  float* h      = (float*)(ws + (1L << 16));         // 3.15 MB        [persist]
  char*  U      = ws + (4L << 20);
  float* norms  = (float*)(U);                       // 80 KB          [kNN phase]
  float* scores = (float*)(U + (1L << 20));          // 39.1 MB        [kNN phase]
  float* xc     = (float*)(U);                       // 18.9 MB        [gather->fc only]
  float* a      = (float*)(U);                       // 3.15 MB        [transformer]
  float* qkv    = (float*)(U + (4L << 20));          // 9.44 MB
  float* S      = (float*)(U + (14L << 20));         // 25.2 MB
  float* o      = (float*)(U + (40L << 20));         // 3.15 MB
  float* ff     = (float*)(U + (44L << 20));         // 12.6 MB -> ends ~57 MB
  (void)ws_size; (void)in_sizes; (void)n_in; (void)out_size;

  const long sQKVb = (long)CT * C3D;   // per-batch stride in qkv
  const long sSb = (long)CH * CT * CT; // per-batch stride in S
  const long sSh = (long)CT * CT;

  // ---- 1. memory norms
  norms_k<<<CB * CM, 256, 0, stream>>>(memory, norms);

  // ---- 2. scores = 2 * input @ memory^T - ||m||^2   [B,T,M]
  gemm_k<64, 64, 16, 4, 4, true, EPI_SCORES>
      <<<dim3((CM + 63) / 64, CT / 64, CB), 256, 0, stream>>>(
          input, memory, nullptr, norms, scores,
          CT, CM, CD, CD, CD, CM,
          1, (long)CT * CD, 0, (long)CM * CD, 0, (long)CT * CM, 0, 0.f);

  // ---- 3. exact top-5 per (b,t)
  topk_k<<<CB * CT, 256, 0, stream>>>(scores, topk);

  // ---- 4. gather retrieved + concat
  gather_k<<<CB * CT, 256, 0, stream>>>(input, memory, topk, xc);

  // ---- 5. fc fuse + wpe:  h = xc @ fc_w + fc_b + wpe[t]
  gemm_k<128, 128, 16, 8, 8, false, EPI_BIAS_WPE>
      <<<dim3(CD / 128, (CB * CT) / 128, 1), 256, 0, stream>>>(
          xc, fc_w, fc_b, wpe, h,
          CB * CT, CD, CIN, CIN, CD, CD,
          1, 0, 0, 0, 0, 0, 0, 0.f);

  // ---- 6. transformer layers
  for (int l = 0; l < CL; ++l) {
    // ln1
    ln_k<<<CB * CT, 256, 0, stream>>>(h, ln1_g + l * CD, ln1_b + l * CD, a);
    // qkv = a @ attn_w[l] + attn_b[l]
    gemm_k<128, 128, 16, 8, 8, false, EPI_BIAS>
        <<<dim3(C3D / 128, (CB * CT) / 128, 1), 256, 0, stream>>>(
            a, attn_w + (long)l * CD * C3D, attn_b + (long)l * C3D, nullptr, qkv,
            CB * CT, C3D, CD, CD, C3D, C3D,
            1, 0, 0, 0, 0, 0, 0, 0.f);
    // S = scale * Q @ K^T (per b,h); fully-masked tiles skipped
    gemm_k<64, 64, 16, 4, 4, true, EPI_SCALE>
        <<<dim3(CT / 64, CT / 64, CB * CH), 256, 0, stream>>>(
            qkv, qkv + CD, nullptr, nullptr, S,
            CT, CT, CHD, C3D, C3D, CT,
            CH, sQKVb, CHD, sQKVb, CHD, sSb, sSh, CSCALE);
    // causal softmax in place
    softmax_k<<<dim3(CT, CB * CH), 128, 0, stream>>>(S);
    // o = P @ V  -> o[b, q, h*64+d]
    gemm_k<64, 64, 16, 4, 4, false, EPI_NONE>
        <<<dim3(1, CT / 64, CB * CH), 256, 0, stream>>>(
            S, qkv + 2 * CD, nullptr, nullptr, o,
            CT, CHD, CT, CT, C3D, CD,
            CH, sSb, sSh, sQKVb, CHD, (long)CT * CD, CHD, 0.f);
    // h = h + o @ proj_w[l] + proj_b[l]
    gemm_k<128, 128, 16, 8, 8, false, EPI_BIAS_RES>
        <<<dim3(CD / 128, (CB * CT) / 128, 1), 256, 0, stream>>>(
            o, proj_w + (long)l * CD * CD, proj_b + (long)l * CD, h, h,
            CB * CT, CD, CD, CD, CD, CD,
            1, 0, 0, 0, 0, 0, 0, 0.f);
    // ln2
    ln_k<<<CB * CT, 256, 0, stream>>>(h, ln2_g + l * CD, ln2_b + l * CD, a);
    // ff = gelu(a @ mlp_fc_w[l] + mlp_fc_b[l])
    gemm_k<128, 128, 16, 8, 8, false, EPI_BIAS_GELU>
        <<<dim3(CFF / 128, (CB * CT) / 128, 1), 256, 0, stream>>>(
            a, mfc_w + (long)l * CD * CFF, mfc_b + (long)l * CFF, nullptr, ff,
            CB * CT, CFF, CD, CD, CFF, CFF,
            1, 0, 0, 0, 0, 0, 0, 0.f);
    // h = h + ff @ mlp_proj_w[l] + mlp_proj_b[l]
    gemm_k<128, 128, 16, 8, 8, false, EPI_BIAS_RES>
        <<<dim3(CD / 128, (CB * CT) / 128, 1), 256, 0, stream>>>(
            ff, mpj_w + (long)l * CFF * CD, mpj_b + (long)l * CD, h, h,
            CB * CT, CD, CFF, CFF, CD, CD,
            1, 0, 0, 0, 0, 0, 0, 0.f);
  }

  // ---- 7. final LN
  ln_k<<<CB * CT, 256, 0, stream>>>(h, lnf_g, lnf_b, a);

  // ---- 8. logits = a @ wte^T   [B*T, V]
  gemm_k<128, 128, 16, 8, 8, true, EPI_NONE>
      <<<dim3((CV + 127) / 128, (CB * CT) / 128, 1), 256, 0, stream>>>(
          a, wte, nullptr, nullptr, out,
          CB * CT, CV, CD, CD, CD, CV,
          1, 0, 0, 0, 0, 0, 0, 0.f);
}

// Round 2
// 4771.853 us; speedup vs baseline: 3.4627x; 3.4627x over previous
//
#include <hip/hip_runtime.h>
#include <math.h>

// ---------------------------------------------------------------------------
// VardaGPT associative forward, v2: bf16 MFMA for all transformer GEMMs,
// fp32 exact kNN retrieval path. B=2 T=512 D=768 M=10000 K=5 L=12 H=12 V=50257.
// ---------------------------------------------------------------------------

#define DEVFN static __device__ __forceinline__

constexpr int CB = 2;
constexpr int CT = 512;
constexpr int CD = 768;
constexpr int CM = 10000;
constexpr int CK = 5;
constexpr int CL = 12;
constexpr int CH = 12;
constexpr int CV = 50257;
constexpr int CFF = 3072;
constexpr int C3D = 2304;
constexpr int CIN = CD + CK * CD;  // 4608
constexpr float CSCALE = 0.125f;

enum { EPI_NONE = 0, EPI_BIAS = 1, EPI_SCORES = 2, EPI_BIAS_WPE = 3,
       EPI_BIAS_RES = 4, EPI_BIAS_GELU = 5, EPI_SCALE = 6 };

typedef __attribute__((ext_vector_type(8))) short short8;
typedef __attribute__((ext_vector_type(4))) short short4v;
typedef __attribute__((ext_vector_type(4))) float f32x4;

DEVFN short f2bf(float f) {  // RNE float->bf16
  unsigned u = __float_as_uint(f);
  unsigned r = (u + 0x7fffu + ((u >> 16) & 1u)) >> 16;
  return (short)r;
}

// ---------------------------------------------------------------------------
// bf16 MFMA GEMM: C[m,n] = sum_k A[m,k]*B'[n,k]  (A bf16 row-major, k contig)
// BMODE 0: B bf16 [N][ldb] (k contig)      -- attention operands
// BMODE 1: B fp32 [K][ldb=N] (n contig)    -- weights, transposed while staging
// BMODE 2: B fp32 [N][ldb] (k contig)      -- wte
// 256 threads = 4 waves (2x2), wave tile (BM/2)x(BN/2), 16x16x32 bf16 MFMA.
// M % BM == 0 and K % 64 == 0 for all uses; N guarded.
// ---------------------------------------------------------------------------
template <int BM, int BN, int BMODE, int EPI, bool OUTBF>
__global__ __launch_bounds__(256) void mgemm_k(
    const short* __restrict__ A, const void* __restrict__ Bvp,
    const float* __restrict__ bias, const float* extra,
    void* Cout,
    int Mdim, int Ndim, int Kdim, int lda, int ldb, int ldc,
    int H2, long sAb, long sAh, long sBb, long sBh, long sCb, long sCh,
    float p0) {
  constexpr int BK = 64;
  constexpr int SK = 72;                 // padded LDS k-stride (bf16 elems)
  constexpr int WTM = BM / 2, WTN = BN / 2;
  constexpr int FM = WTM / 16, FN = WTN / 16;

  const int n0 = blockIdx.x * BN;
  const int m0 = blockIdx.y * BM;
  if (EPI == EPI_SCALE && n0 > m0 + BM - 1) return;  // fully-masked causal tile

  const int z = blockIdx.z;
  const int zb = z / H2, zh = z % H2;
  A += zb * sAb + zh * sAh;
  const short* Bs16 = (const short*)Bvp + zb * sBb + zh * sBh;
  const float* Bf32 = (const float*)Bvp + zb * sBb + zh * sBh;

  __shared__ short As[BM * SK];
  __shared__ short Bs[BN * SK];

  const int tid = threadIdx.x;
  const int wid = tid >> 6;
  const int wr = wid >> 1, wc = wid & 1;
  const int lane = tid & 63;
  const int lr = lane & 15, ls = lane >> 4;

  f32x4 acc[FM][FN];
#pragma unroll
  for (int i = 0; i < FM; ++i)
#pragma unroll
    for (int j = 0; j < FN; ++j) acc[i][j] = (f32x4)0.f;

  for (int k0 = 0; k0 < Kdim; k0 += BK) {
    // ---- stage A (bf16, 16B chunks)
#pragma unroll
    for (int it = 0; it < BM * 8 / 256; ++it) {
      int s = tid + it * 256;
      int row = s >> 3, c = s & 7;
      int4 v = *reinterpret_cast<const int4*>(A + (long)(m0 + row) * lda + k0 + c * 8);
      *reinterpret_cast<int4*>(&As[row * SK + c * 8]) = v;
    }
    // ---- stage B
    if (BMODE == 0) {
#pragma unroll
      for (int it = 0; it < BN * 8 / 256; ++it) {
        int s = tid + it * 256;
        int row = s >> 3, c = s & 7;
        int4 v = make_int4(0, 0, 0, 0);
        if (n0 + row < Ndim)
          v = *reinterpret_cast<const int4*>(Bs16 + (long)(n0 + row) * ldb + k0 + c * 8);
        *reinterpret_cast<int4*>(&Bs[row * SK + c * 8]) = v;
      }
    } else if (BMODE == 1) {  // fp32 [K][N], transpose while staging
#pragma unroll
      for (int it = 0; it < BK * (BN / 4) / 256; ++it) {
        int s = tid + it * 256;
        int kr = s / (BN / 4), nc = (s % (BN / 4)) * 4;
        float4 w = *reinterpret_cast<const float4*>(Bf32 + (long)(k0 + kr) * ldb + n0 + nc);
        Bs[(nc + 0) * SK + kr] = f2bf(w.x);
        Bs[(nc + 1) * SK + kr] = f2bf(w.y);
        Bs[(nc + 2) * SK + kr] = f2bf(w.z);
        Bs[(nc + 3) * SK + kr] = f2bf(w.w);
      }
    } else {  // BMODE 2: fp32 [N][K]
#pragma unroll
      for (int it = 0; it < BN * 16 / 256; ++it) {
        int s = tid + it * 256;
        int row = s >> 4, c = (s & 15) * 4;
        short4v o = {0, 0, 0, 0};
        if (n0 + row < Ndim) {
          float4 w = *reinterpret_cast<const float4*>(Bf32 + (long)(n0 + row) * ldb + k0 + c);
          o.x = f2bf(w.x); o.y = f2bf(w.y); o.z = f2bf(w.z); o.w = f2bf(w.w);
        }
        *reinterpret_cast<short4v*>(&Bs[row * SK + c]) = o;
      }
    }
    __syncthreads();

#pragma unroll
    for (int kk = 0; kk < BK; kk += 32) {
      short8 af[FM], bfr[FN];
#pragma unroll
      for (int i = 0; i < FM; ++i)
        af[i] = *reinterpret_cast<const short8*>(
            &As[(wr * WTM + i * 16 + lr) * SK + kk + ls * 8]);
#pragma unroll
      for (int j = 0; j < FN; ++j)
        bfr[j] = *reinterpret_cast<const short8*>(
            &Bs[(wc * WTN + j * 16 + lr) * SK + kk + ls * 8]);
#pragma unroll
      for (int i = 0; i < FM; ++i)
#pragma unroll
        for (int j = 0; j < FN; ++j)
          acc[i][j] = __builtin_amdgcn_mfma_f32_16x16x32_bf16(af[i], bfr[j], acc[i][j], 0, 0, 0);
    }
    __syncthreads();
  }

  // ---- epilogue
  float* Cf = (float*)Cout + zb * sCb + zh * sCh;
  short* Cb = (short*)Cout + zb * sCb + zh * sCh;
#pragma unroll
  for (int i = 0; i < FM; ++i) {
    const int rm = m0 + wr * WTM + i * 16 + ls * 4;
#pragma unroll
    for (int j = 0; j < FN; ++j) {
      const int n = n0 + wc * WTN + j * 16 + lr;
      if (n >= Ndim) continue;
#pragma unroll
      for (int r = 0; r < 4; ++r) {
        const int m = rm + r;
        float v = acc[i][j][r];
        if (EPI == EPI_BIAS || EPI == EPI_BIAS_WPE || EPI == EPI_BIAS_RES ||
            EPI == EPI_BIAS_GELU)
          v += bias[n];
        if (EPI == EPI_BIAS_WPE) v += extra[(long)(m % CT) * Ndim + n];
        if (EPI == EPI_BIAS_RES) v += extra[(long)m * ldc + n];
        if (EPI == EPI_BIAS_GELU) {
          float x = v;
          v = 0.5f * x * (1.f + tanhf(0.7978845608028654f * (x + 0.044715f * x * x * x)));
        }
        if (EPI == EPI_SCALE) v *= p0;
        if (OUTBF) Cb[(long)m * ldc + n] = f2bf(v);
        else       Cf[(long)m * ldc + n] = v;
      }
    }
  }
}

// ---------------------------------------------------------------------------
// fp32 tiled GEMM (scores only): C = 2*(A @ B^T) - norms, exact retrieval math
// ---------------------------------------------------------------------------
template <int BM, int BN, int BK, int TM, int TN>
__global__ __launch_bounds__(256) void sgemm_k(
    const float* __restrict__ A, const float* __restrict__ Bp,
    const float* __restrict__ norms, float* __restrict__ C,
    int Mdim, int Ndim, int Kdim) {
  const int n0 = blockIdx.x * BN;
  const int m0 = blockIdx.y * BM;
  const int zb = blockIdx.z;
  A += (long)zb * CT * CD;
  Bp += (long)zb * CM * CD;
  C += (long)zb * CT * CM;
  norms += (long)zb * CM;

  __shared__ float As[BK][BM + 4];
  __shared__ float Bs[BK][BN + 4];
  const int tid = threadIdx.x;
  const int tx = tid % (BN / TN);
  const int ty = tid / (BN / TN);

  float acc[TM][TN];
#pragma unroll
  for (int i = 0; i < TM; ++i)
#pragma unroll
    for (int j = 0; j < TN; ++j) acc[i][j] = 0.f;

  for (int k0 = 0; k0 < Kdim; k0 += BK) {
#pragma unroll
    for (int it = 0; it < BM * BK / 4 / 256; ++it) {
      int s = tid + it * 256;
      int row = s / (BK / 4), kg = (s % (BK / 4)) * 4;
      float4 v = *reinterpret_cast<const float4*>(A + (long)(m0 + row) * Kdim + k0 + kg);
      As[kg + 0][row] = v.x; As[kg + 1][row] = v.y;
      As[kg + 2][row] = v.z; As[kg + 3][row] = v.w;
    }
#pragma unroll
    for (int it = 0; it < BN * BK / 4 / 256; ++it) {
      int s = tid + it * 256;
      int row = s / (BK / 4), kg = (s % (BK / 4)) * 4;
      float4 v = make_float4(0.f, 0.f, 0.f, 0.f);
      if (n0 + row < Ndim)
        v = *reinterpret_cast<const float4*>(Bp + (long)(n0 + row) * Kdim + k0 + kg);
      Bs[kg + 0][row] = v.x; Bs[kg + 1][row] = v.y;
      Bs[kg + 2][row] = v.z; Bs[kg + 3][row] = v.w;
    }
    __syncthreads();
#pragma unroll
    for (int k = 0; k < BK; ++k) {
      float ra[TM], rb[TN];
#pragma unroll
      for (int i = 0; i < TM; ++i) ra[i] = As[k][ty * TM + i];
#pragma unroll
      for (int j = 0; j < TN; ++j) rb[j] = Bs[k][tx * TN + j];
#pragma unroll
      for (int i = 0; i < TM; ++i)
#pragma unroll
        for (int j = 0; j < TN; ++j) acc[i][j] += ra[i] * rb[j];
    }
    __syncthreads();
  }
#pragma unroll
  for (int i = 0; i < TM; ++i) {
    int m = m0 + ty * TM + i;
#pragma unroll
    for (int j = 0; j < TN; ++j) {
      int n = n0 + tx * TN + j;
      if (n < Ndim) C[(long)m * Ndim + n] = 2.f * acc[i][j] - norms[n];
    }
  }
}

// ---------------------------------------------------------------------------
__global__ __launch_bounds__(256) void norms_k(const float* __restrict__ mem,
                                               float* __restrict__ norms) {
  __shared__ float red[256];
  const int row = blockIdx.x;
  const int tid = threadIdx.x;
  const float* r = mem + (long)row * CD;
  float s = 0.f;
  for (int i = tid; i < CD; i += 256) { float v = r[i]; s += v * v; }
  red[tid] = s;
  __syncthreads();
  for (int off = 128; off > 0; off >>= 1) {
    if (tid < off) red[tid] += red[tid + off];
    __syncthreads();
  }
  if (tid == 0) norms[row] = red[0];
}

// ---------------------------------------------------------------------------
DEVFN bool tk_better(float as, int ai, float bs, int bi) {
  return (as > bs) || (as == bs && ai < bi);
}
DEVFN void tk_insert(float s[5], int id[5], float cs, int ci) {
  if (!tk_better(cs, ci, s[4], id[4])) return;
  s[4] = cs; id[4] = ci;
#pragma unroll
  for (int j = 4; j > 0; --j) {
    if (tk_better(s[j], id[j], s[j - 1], id[j - 1])) {
      float ts = s[j]; s[j] = s[j - 1]; s[j - 1] = ts;
      int ti = id[j]; id[j] = id[j - 1]; id[j - 1] = ti;
    }
  }
}

__global__ __launch_bounds__(256) void topk_k(const float* __restrict__ scores,
                                              int* __restrict__ out) {
  __shared__ float ss[256 * 5];
  __shared__ int si[256 * 5];
  const int row = blockIdx.x;
  const int tid = threadIdx.x;
  const float* sr = scores + (long)row * CM;
  float bs[5]; int bi[5];
#pragma unroll
  for (int j = 0; j < 5; ++j) { bs[j] = -3.0e38f; bi[j] = 0x7fffffff; }
  for (int m = tid; m < CM; m += 256) tk_insert(bs, bi, sr[m], m);
#pragma unroll
  for (int j = 0; j < 5; ++j) { ss[tid * 5 + j] = bs[j]; si[tid * 5 + j] = bi[j]; }
  // tree merge
  for (int off = 128; off > 0; off >>= 1) {
    __syncthreads();
    if (tid < off) {
      float ms[5]; int mi[5];
#pragma unroll
      for (int j = 0; j < 5; ++j) { ms[j] = ss[tid * 5 + j]; mi[j] = si[tid * 5 + j]; }
#pragma unroll
      for (int j = 0; j < 5; ++j)
        tk_insert(ms, mi, ss[(tid + off) * 5 + j], si[(tid + off) * 5 + j]);
#pragma unroll
      for (int j = 0; j < 5; ++j) { ss[tid * 5 + j] = ms[j]; si[tid * 5 + j] = mi[j]; }
    }
  }
  __syncthreads();
  if (tid < 5) out[row * CK + tid] = si[tid];
}

// ---------------------------------------------------------------------------
// gather concat -> bf16 xc
// ---------------------------------------------------------------------------
__global__ __launch_bounds__(256) void gather_k(const float* __restrict__ inp,
                                                const float* __restrict__ mem,
                                                const int* __restrict__ idx,
                                                short* __restrict__ xc) {
  __shared__ int sid[5];
  const int row = blockIdx.x;
  const int b = row / CT;
  const int tid = threadIdx.x;
  if (tid < 5) sid[tid] = idx[row * CK + tid];
  __syncthreads();
  short* dst = xc + (long)row * CIN;
  const float* s0 = inp + (long)row * CD;
  for (int i = tid; i < CD; i += 256) dst[i] = f2bf(s0[i]);
#pragma unroll
  for (int k = 0; k < 5; ++k) {
    const float* ms = mem + ((long)b * CM + sid[k]) * CD;
    for (int i = tid; i < CD; i += 256) dst[CD + k * CD + i] = f2bf(ms[i]);
  }
}

// ---------------------------------------------------------------------------
// LayerNorm: fp32 in -> bf16 out (GEMM input)
// ---------------------------------------------------------------------------
__global__ __launch_bounds__(256) void ln_k(const float* __restrict__ x,
                                            const float* __restrict__ g,
                                            const float* __restrict__ bb,
                                            short* __restrict__ y) {
  __shared__ float red[256];
  const int row = blockIdx.x;
  const int tid = threadIdx.x;
  const float* xr = x + (long)row * CD;
  float v0 = xr[tid], v1 = xr[tid + 256], v2 = xr[tid + 512];
  red[tid] = v0 + v1 + v2;
  __syncthreads();
  for (int off = 128; off > 0; off >>= 1) {
    if (tid < off) red[tid] += red[tid + off];
    __syncthreads();
  }
  const float mu = red[0] * (1.f / 768.f);
  __syncthreads();
  const float d0 = v0 - mu, d1 = v1 - mu, d2 = v2 - mu;
  red[tid] = d0 * d0 + d1 * d1 + d2 * d2;
  __syncthreads();
  for (int off = 128; off > 0; off >>= 1) {
    if (tid < off) red[tid] += red[tid + off];
    __syncthreads();
  }
  const float rstd = rsqrtf(red[0] * (1.f / 768.f) + 1e-5f);
  short* yr = y + (long)row * CD;
  yr[tid]       = f2bf(d0 * rstd * g[tid] + bb[tid]);
  yr[tid + 256] = f2bf(d1 * rstd * g[tid + 256] + bb[tid + 256]);
  yr[tid + 512] = f2bf(d2 * rstd * g[tid + 512] + bb[tid + 512]);
}

// ---------------------------------------------------------------------------
// causal softmax: S fp32 in, P bf16 out (masked -> 0)
// ---------------------------------------------------------------------------
__global__ __launch_bounds__(128) void softmax_k(const float* __restrict__ S,
                                                 short* __restrict__ P) {
  __shared__ float red[128];
  const int q = blockIdx.x;
  const long base = (long)blockIdx.y * (CT * (long)CT) + (long)q * CT;
  const int tid = threadIdx.x;
  float v[4];
#pragma unroll
  for (int i = 0; i < 4; ++i) {
    int k = tid + i * 128;
    v[i] = (k <= q) ? S[base + k] : -1e30f;
  }
  float m = fmaxf(fmaxf(v[0], v[1]), fmaxf(v[2], v[3]));
  red[tid] = m;
  __syncthreads();
  for (int off = 64; off > 0; off >>= 1) {
    if (tid < off) red[tid] = fmaxf(red[tid], red[tid + off]);
    __syncthreads();
  }
  m = red[0];
  __syncthreads();
  float e[4]; float sum = 0.f;
#pragma unroll
  for (int i = 0; i < 4; ++i) { e[i] = expf(v[i] - m); sum += e[i]; }
  red[tid] = sum;
  __syncthreads();
  for (int off = 64; off > 0; off >>= 1) {
    if (tid < off) red[tid] += red[tid + off];
    __syncthreads();
  }
  const float inv = 1.f / red[0];
#pragma unroll
  for (int i = 0; i < 4; ++i) {
    int k = tid + i * 128;
    P[base + k] = (k <= q) ? f2bf(e[i] * inv) : (short)0;
  }
}

// ---------------------------------------------------------------------------
// V transpose: vt[z][d][t] = qkv[b][t][2D + h*64 + d]  (bf16)
// ---------------------------------------------------------------------------
__global__ __launch_bounds__(256) void vt_k(const short* __restrict__ qkv,
                                            short* __restrict__ vt) {
  __shared__ short tile[32][33];
  const int z = blockIdx.z;
  const int zb = z / CH, zh = z % CH;
  const int t0 = blockIdx.x * 32, d0 = blockIdx.y * 32;
  const int tx = threadIdx.x & 31, ty = threadIdx.x >> 5;
#pragma unroll
  for (int i = 0; i < 4; ++i) {
    int t = t0 + ty + i * 8;
    tile[ty + i * 8][tx] = qkv[(long)zb * CT * C3D + (long)t * C3D + 2 * CD + zh * 64 + d0 + tx];
  }
  __syncthreads();
#pragma unroll
  for (int i = 0; i < 4; ++i) {
    int d = d0 + ty + i * 8;
    vt[(long)z * 64 * CT + (long)d * CT + t0 + tx] = tile[tx][ty + i * 8];
  }
}

// ---------------------------------------------------------------------------
extern "C" void kernel_launch(void* const* d_in, const int* in_sizes, int n_in,
                              void* d_out, int out_size, void* d_ws, size_t ws_size,
                              hipStream_t stream) {
  const float* input  = (const float*)d_in[0];
  const float* memory = (const float*)d_in[1];
  const float* fc_w   = (const float*)d_in[2];
  const float* fc_b   = (const float*)d_in[3];
  const float* wpe    = (const float*)d_in[4];
  const float* wte    = (const float*)d_in[5];
  const float* ln1_g  = (const float*)d_in[6];
  const float* ln1_b  = (const float*)d_in[7];
  const float* attn_w = (const float*)d_in[8];
  const float* attn_b = (const float*)d_in[9];
  const float* proj_w = (const float*)d_in[10];
  const float* proj_b = (const float*)d_in[11];
  const float* ln2_g  = (const float*)d_in[12];
  const float* ln2_b  = (const float*)d_in[13];
  const float* mfc_w  = (const float*)d_in[14];
  const float* mfc_b  = (const float*)d_in[15];
  const float* mpj_w  = (const float*)d_in[16];
  const float* mpj_b  = (const float*)d_in[17];
  const float* lnf_g  = (const float*)d_in[18];
  const float* lnf_b  = (const float*)d_in[19];
  float* out = (float*)d_out;
  char* ws = (char*)d_ws;
  (void)in_sizes; (void)n_in; (void)out_size; (void)ws_size;

  // ---- workspace layout (bytes) ----
  const long MB = 1L << 20;
  int*   topk   = (int*)(ws);                  // 20 KB
  float* h      = (float*)(ws + 1 * MB);       // 3.15 MB   [1024][768] f32
  short* a_bf   = (short*)(ws + 5 * MB);       // 1.58 MB   [1024][768] bf16
  short* qkv_bf = (short*)(ws + 7 * MB);       // 4.72 MB   [1024][2304] bf16
  float* S      = (float*)(ws + 12 * MB);      // 25.2 MB   [24][512][512] f32
  short* P      = (short*)(ws + 38 * MB);      // 12.6 MB   [24][512][512] bf16
  short* vt     = (short*)(ws + 51 * MB);      // 1.58 MB   [24][64][512] bf16
  short* o_bf   = (short*)(ws + 53 * MB);      // 1.58 MB   [1024][768] bf16
  short* ff_bf  = (short*)(ws + 55 * MB);      // 6.3 MB    [1024][3072] bf16
  float* norms  = (float*)(ws + 62 * MB);      // 80 KB
  float* scores = (float*)(ws + 63 * MB);      // 41 MB     [2][512][10000] f32
  short* xc_bf  = (short*)(ws + 63 * MB);      // 9.4 MB    aliases scores (dead)
  // end ~104 MB

  const long sQKV = (long)CT * C3D;
  const long sS = (long)CT * CT;

  // ---- retrieval (exact fp32) ----
  norms_k<<<CB * CM, 256, 0, stream>>>(memory, norms);
  sgemm_k<128, 128, 16, 8, 8>
      <<<dim3((CM + 127) / 128, CT / 128, CB), 256, 0, stream>>>(
          input, memory, norms, scores, CT, CM, CD);
  topk_k<<<CB * CT, 256, 0, stream>>>(scores, topk);
  gather_k<<<CB * CT, 256, 0, stream>>>(input, memory, topk, xc_bf);

  // ---- fc fuse + wpe -> h (fp32) ----
  mgemm_k<64, 64, 1, EPI_BIAS_WPE, false>
      <<<dim3(CD / 64, (CB * CT) / 64, 1), 256, 0, stream>>>(
          xc_bf, fc_w, fc_b, wpe, h,
          CB * CT, CD, CIN, CIN, CD, CD, 1, 0, 0, 0, 0, 0, 0, 0.f);

  // ---- transformer ----
  for (int l = 0; l < CL; ++l) {
    ln_k<<<CB * CT, 256, 0, stream>>>(h, ln1_g + l * CD, ln1_b + l * CD, a_bf);
    mgemm_k<64, 64, 1, EPI_BIAS, true>
        <<<dim3(C3D / 64, (CB * CT) / 64, 1), 256, 0, stream>>>(
            a_bf, attn_w + (long)l * CD * C3D, attn_b + (long)l * C3D, nullptr, qkv_bf,
            CB * CT, C3D, CD, CD, C3D, C3D, 1, 0, 0, 0, 0, 0, 0, 0.f);
    mgemm_k<64, 64, 0, EPI_SCALE, false>
        <<<dim3(CT / 64, CT / 64, CB * CH), 256, 0, stream>>>(
            qkv_bf, qkv_bf + CD, nullptr, nullptr, S,
            CT, CT, 64, C3D, C3D, CT,
            CH, sQKV, 64, sQKV, 64, (long)CH * sS, sS, CSCALE);
    softmax_k<<<dim3(CT, CB * CH), 128, 0, stream>>>(S, P);
    vt_k<<<dim3(CT / 32, 2, CB * CH), 256, 0, stream>>>(qkv_bf, vt);
    mgemm_k<64, 64, 0, EPI_NONE, true>
        <<<dim3(1, CT / 64, CB * CH), 256, 0, stream>>>(
            P, vt, nullptr, nullptr, o_bf,
            CT, 64, CT, CT, CT, CD,
            CH, (long)CH * sS, sS, (long)CH * 64 * CT, (long)64 * CT,
            (long)CT * CD, 64, 0.f);
    mgemm_k<64, 64, 1, EPI_BIAS_RES, false>
        <<<dim3(CD / 64, (CB * CT) / 64, 1), 256, 0, stream>>>(
            o_bf, proj_w + (long)l * CD * CD, proj_b + (long)l * CD, h, h,
            CB * CT, CD, CD, CD, CD, CD, 1, 0, 0, 0, 0, 0, 0, 0.f);
    ln_k<<<CB * CT, 256, 0, stream>>>(h, ln2_g + l * CD, ln2_b + l * CD, a_bf);
    mgemm_k<64, 64, 1, EPI_BIAS_GELU, true>
        <<<dim3(CFF / 64, (CB * CT) / 64, 1), 256, 0, stream>>>(
            a_bf, mfc_w + (long)l * CD * CFF, mfc_b + (long)l * CFF, nullptr, ff_bf,
            CB * CT, CFF, CD, CD, CFF, CFF, 1, 0, 0, 0, 0, 0, 0, 0.f);
    mgemm_k<64, 64, 1, EPI_BIAS_RES, false>
        <<<dim3(CD / 64, (CB * CT) / 64, 1), 256, 0, stream>>>(
            ff_bf, mpj_w + (long)l * CFF * CD, mpj_b + (long)l * CD, h, h,
            CB * CT, CD, CFF, CFF, CD, CD, 1, 0, 0, 0, 0, 0, 0, 0.f);
  }

  // ---- final LN + logits ----
  ln_k<<<CB * CT, 256, 0, stream>>>(h, lnf_g, lnf_b, a_bf);
  mgemm_k<128, 128, 2, EPI_NONE, false>
      <<<dim3((CV + 127) / 128, (CB * CT) / 128, 1), 256, 0, stream>>>(
          a_bf, wte, nullptr, nullptr, out,
          CB * CT, CV, CD, CD, CD, CV, 1, 0, 0, 0, 0, 0, 0, 0.f);
}